// Round 3
// baseline (146.587 us; speedup 1.0000x reference)
//
#include <hip/hip_runtime.h>
#include <math.h>

// Second-order IIR (B=1024 rows, T=16384), fp32.
// One row per block, 256 threads = 4 waves; 4 blocks/CU (one residency wave).
// Per half (8192 elems): each WAVE autonomously handles a 2048-elem segment:
//   coalesced global float4 loads -> ds_write_b128 into own padded LDS region
//   -> ds_read_b128 per-lane 32-elem chunks (wave-local transpose, no barrier)
//   -> FIR + zero-state chunk response (v kept in VGPRs)
//   -> in-wave Kogge-Stone affine scan (uniform-matrix form, vector-only shuffles)
//   -> ONE __syncthreads -> 4-way cross-wave combine -> exact pass2
//   -> y via ds_write_b128 -> coalesced drain.
// 2 block barriers total. Half-2 global loads prefetched during half-1 scan.
//
// LDS padding: element i of a wave's segment lives at float index i + 4*(i>>5)
// (pad 4 floats per 32). float4-slot views: stage g -> g + (g>>3); chunk read
// lane l, j -> 9l + j. Both are Latin squares mod 8 -> even 8-lanes/bank-group,
// the b128 minimum (no extra conflicts).

#define TLEN  16384
#define HALF  8192
#define NT    256
#define NW    4
#define SEG   2048                    // elements per wave per half
#define WPAD  2304                    // padded floats per wave region
#define SUMS  (NW * WPAD)             // 9216: wave summaries [2 halves][4 waves][2]
#define CARRY (SUMS + 16)             // inter-half carry (2 floats)
#define LDSF  (CARRY + 2)

struct M2 { float a, b, c, d; };      // [[a,b],[c,d]]
__device__ __forceinline__ M2 mmul(const M2& x, const M2& y) {
    M2 r;
    r.a = fmaf(x.a, y.a, x.b * y.c);
    r.b = fmaf(x.a, y.b, x.b * y.d);
    r.c = fmaf(x.c, y.a, x.d * y.c);
    r.d = fmaf(x.c, y.b, x.d * y.d);
    return r;
}

__global__ __launch_bounds__(NT, 4)
void iir_kernel(const float* __restrict__ bc,
                const float* __restrict__ rho_p,
                const float* __restrict__ psi_p,
                const float* __restrict__ u_in,
                const float* __restrict__ y_init,
                const float* __restrict__ u_init,
                float* __restrict__ y_out)
{
    __shared__ __align__(16) float lds[LDSF];
    const int row = blockIdx.x;
    const int tid = threadIdx.x;
    const int w   = tid >> 6;         // wave id
    const int l   = tid & 63;         // lane
    float* wreg = lds + w * WPAD;     // this wave's padded region (16B-aligned)

    const float rho = rho_p[0];
    const float psi = psi_p[0];
    const float r   = 1.0f / (1.0f + expf(-rho));
    const float th  = 3.14159265358979323846f / (1.0f + expf(-psi));
    const float a1  = -2.0f * r * cosf(th);
    const float a2  = r * r;
    const float b0  = bc[0], b1 = bc[1], b2 = bc[2];

    // M = A^32 (A = [[-a1,-a2],[1,0]]), P = M^lane, Mseg = M^64  (half-invariant)
    M2 M = { -a1, -a2, 1.0f, 0.0f };
    #pragma unroll
    for (int s = 0; s < 5; ++s) M = mmul(M, M);
    M2 W = M, P = { 1.0f, 0.0f, 0.0f, 1.0f };
    #pragma unroll
    for (int p = 0; p < 6; ++p) {
        if ((l >> p) & 1) P = mmul(W, P);   // powers of same base commute
        W = mmul(W, W);
    }
    const M2 Mseg = W;                // A^2048

    const float* urow = u_in  + (size_t)row * TLEN;
    float*       orow = y_out + (size_t)row * TLEN;

    // prefetch half 0 (coalesced: lane l, float4 index l + 64k within segment)
    float4 st[8];
    {
        const float4* us = (const float4*)(urow + w * SEG);
        #pragma unroll
        for (int k = 0; k < 8; ++k) st[k] = us[l + 64 * k];
    }

    for (int h = 0; h < 2; ++h) {
        // ---- stage into own LDS region (b128, padded) ----
        #pragma unroll
        for (int k = 0; k < 8; ++k) {
            int g = l + 64 * k;
            *(float4*)&wreg[4 * (g + (g >> 3))] = st[k];
        }
        __threadfence_block();        // lgkmcnt(0): wave-local writes visible

        // ---- transpose read: lane's 32-elem chunk ----
        float uu[32];
        #pragma unroll
        for (int j = 0; j < 8; ++j)
            *(float4*)&uu[4 * j] = *(const float4*)&wreg[4 * (9 * l + j)];

        // ---- chunk boundary u's via shuffle (lane 0: global / u_init) ----
        float um2, um1;
        {
            float pm2 = __shfl_up(uu[30], 1);
            float pm1 = __shfl_up(uu[31], 1);
            if (l == 0) {
                int gstart = h * HALF + w * SEG;
                if (gstart == 0) { um2 = u_init[2 * row + 1]; um1 = u_init[2 * row + 0]; }
                else { float2 b = *(const float2*)(urow + gstart - 2); um2 = b.x; um1 = b.y; }
            } else { um2 = pm2; um1 = pm1; }
        }

        // ---- pass 1: FIR into v[] + zero-state chunk response ----
        float v[32];
        float y1 = 0.0f, y2 = 0.0f;
        #pragma unroll
        for (int j = 0; j < 32; ++j) {
            float uc = uu[j];
            float vv = fmaf(b2, um2, fmaf(b1, um1, b0 * uc));
            v[j] = vv;
            float y = fmaf(-a1, y1, fmaf(-a2, y2, vv));
            y2 = y1; y1 = y;
            um2 = um1; um1 = uc;
        }

        // ---- prefetch next half while scan runs ----
        if (h == 0) {
            const float4* us = (const float4*)(urow + HALF + w * SEG);
            #pragma unroll
            for (int k = 0; k < 8; ++k) st[k] = us[l + 64 * k];
        }

        // ---- in-wave Kogge-Stone affine scan (uniform matrix; shuffle vectors only) ----
        float s0 = y1, s1 = y2;
        M2 Wp = M;
        #pragma unroll
        for (int p = 0; p < 6; ++p) {
            float o0 = __shfl_up(s0, 1 << p);
            float o1 = __shfl_up(s1, 1 << p);
            if (l >= (1 << p)) {
                float n0 = fmaf(Wp.a, o0, fmaf(Wp.b, o1, s0));
                float n1 = fmaf(Wp.c, o0, fmaf(Wp.d, o1, s1));
                s0 = n0; s1 = n1;
            }
            if (p < 5) Wp = mmul(Wp, Wp);
        }
        float e0 = __shfl_up(s0, 1);
        float e1 = __shfl_up(s1, 1);
        if (l == 0) { e0 = 0.0f; e1 = 0.0f; }

        if (l == 63) {                // wave summary (zero-state segment response)
            lds[SUMS + 8 * h + 2 * w]     = s0;
            lds[SUMS + 8 * h + 2 * w + 1] = s1;
        }
        __syncthreads();              // ONE barrier per half

        // ---- cross-wave combine (4 summaries; everyone computes) ----
        float t0, t1;                 // seed = state before this half
        if (h == 0) { t0 = y_init[2 * row]; t1 = y_init[2 * row + 1]; }
        else        { t0 = lds[CARRY]; t1 = lds[CARRY + 1]; }
        float c0 = t0, c1 = t1;       // full-advance accumulator (carry)
        #pragma unroll
        for (int j = 0; j < NW; ++j) {
            float q0 = lds[SUMS + 8 * h + 2 * j];
            float q1 = lds[SUMS + 8 * h + 2 * j + 1];
            float n0 = fmaf(Mseg.a, c0, fmaf(Mseg.b, c1, q0));
            float n1 = fmaf(Mseg.c, c0, fmaf(Mseg.d, c1, q1));
            c0 = n0; c1 = n1;
            if (j == w - 1) { t0 = c0; t1 = c1; }   // state before my segment
        }
        if (h == 0 && tid == 0) { lds[CARRY] = c0; lds[CARRY + 1] = c1; } // read after next barrier

        // lane's incoming state: P * wave_in + exclusive prefix
        float in0 = fmaf(P.a, t0, fmaf(P.b, t1, e0));
        float in1 = fmaf(P.c, t0, fmaf(P.d, t1, e1));

        // ---- pass 2: exact recurrence, write y into LDS (b128) ----
        float py1 = in0, py2 = in1;
        #pragma unroll
        for (int j = 0; j < 8; ++j) {
            float x0 = fmaf(-a1, py1, fmaf(-a2, py2, v[4 * j + 0]));
            float x1 = fmaf(-a1, x0,  fmaf(-a2, py1, v[4 * j + 1]));
            float x2 = fmaf(-a1, x1,  fmaf(-a2, x0,  v[4 * j + 2]));
            float x3 = fmaf(-a1, x2,  fmaf(-a2, x1,  v[4 * j + 3]));
            float4 q; q.x = x0; q.y = x1; q.z = x2; q.w = x3;
            *(float4*)&wreg[4 * (9 * l + j)] = q;
            py2 = x2; py1 = x3;
        }
        __threadfence_block();

        // ---- drain: coalesced LDS -> global ----
        float4* os = (float4*)(orow + h * HALF + w * SEG);
        #pragma unroll
        for (int k = 0; k < 8; ++k) {
            int g = l + 64 * k;
            os[g] = *(const float4*)&wreg[4 * (g + (g >> 3))];
        }
        // next half's stage writes only this wave's own region; DS ops complete
        // in order per wave and the stage-top fence waits lgkmcnt(0) -> safe
        // without a block barrier.
    }
}

extern "C" void kernel_launch(void* const* d_in, const int* in_sizes, int n_in,
                              void* d_out, int out_size, void* d_ws, size_t ws_size,
                              hipStream_t stream) {
    const float* bc    = (const float*)d_in[0];
    const float* rho   = (const float*)d_in[1];
    const float* psi   = (const float*)d_in[2];
    const float* u_in  = (const float*)d_in[3];
    const float* y_in  = (const float*)d_in[4];
    const float* u_ini = (const float*)d_in[5];
    float* y = (float*)d_out;
    const int B = in_sizes[3] / TLEN;   // 1024
    iir_kernel<<<B, NT, 0, stream>>>(bc, rho, psi, u_in, y_in, u_ini, y);
}

// Round 4
// 126.473 us; speedup vs baseline: 1.1590x; 1.1590x over previous
//
#include <hip/hip_runtime.h>
#include <math.h>

// Second-order IIR (B=1024 rows, T=16384), fp32.
// One row per block, 256 threads = 4 waves; 4 blocks/CU.
// Per half (8192 elems), each WAVE autonomously handles a 2048-elem segment:
//   coalesced global float4 loads -> ds_write_b128 (padded region, transient regs)
//   -> ds_read_b128 quad + FUSED 3-tap FIR (no uu[] array; v kept as float4 v[8])
//   -> zero-state chunk recurrence -> in-wave Kogge-Stone affine scan
//   -> ONE __syncthreads -> 4-way cross-wave combine -> exact pass2
//   -> y via ds_write_b128 -> coalesced float4 drain.
// 2 block barriers total. NO register prefetch across phases (round-3 spill fix):
// peak live set ~70 VGPRs, everything constant-indexed float4.
//
// LDS padding: element i of a wave's segment at float index i + 4*(i>>5).
// float4-slot views: stage g -> g + (g>>3); chunk read lane l, quad j -> 9l + j.
// Both Latin squares mod 8 -> minimum-phase b128 access (no extra conflicts).

#define TLEN  16384
#define HALF  8192
#define NT    256
#define NW    4
#define SEG   2048                    // elements per wave per half
#define WPAD  2304                    // padded floats per wave region
#define SUMS  (NW * WPAD)             // 9216: wave summaries [2 halves][4 waves][2]
#define CARRY (SUMS + 16)             // inter-half carry (2 floats)
#define LDSF  (CARRY + 2)

struct M2 { float a, b, c, d; };      // [[a,b],[c,d]]
__device__ __forceinline__ M2 mmul(const M2& x, const M2& y) {
    M2 r;
    r.a = fmaf(x.a, y.a, x.b * y.c);
    r.b = fmaf(x.a, y.b, x.b * y.d);
    r.c = fmaf(x.c, y.a, x.d * y.c);
    r.d = fmaf(x.c, y.b, x.d * y.d);
    return r;
}

__global__ __launch_bounds__(NT, 4)
void iir_kernel(const float* __restrict__ bc,
                const float* __restrict__ rho_p,
                const float* __restrict__ psi_p,
                const float* __restrict__ u_in,
                const float* __restrict__ y_init,
                const float* __restrict__ u_init,
                float* __restrict__ y_out)
{
    __shared__ __align__(16) float lds[LDSF];
    const int row = blockIdx.x;
    const int tid = threadIdx.x;
    const int w   = tid >> 6;         // wave id
    const int l   = tid & 63;         // lane
    float* wreg = lds + w * WPAD;     // this wave's padded region (16B-aligned)

    const float rho = rho_p[0];
    const float psi = psi_p[0];
    const float r   = 1.0f / (1.0f + expf(-rho));
    const float th  = 3.14159265358979323846f / (1.0f + expf(-psi));
    const float a1  = -2.0f * r * cosf(th);
    const float a2  = r * r;
    const float b0  = bc[0], b1 = bc[1], b2 = bc[2];

    // M = A^32 (A = [[-a1,-a2],[1,0]]), P = M^lane, Mseg = A^2048 (half-invariant)
    M2 M = { -a1, -a2, 1.0f, 0.0f };
    #pragma unroll
    for (int s = 0; s < 5; ++s) M = mmul(M, M);
    M2 W = M, P = { 1.0f, 0.0f, 0.0f, 1.0f };
    #pragma unroll
    for (int p = 0; p < 6; ++p) {
        if ((l >> p) & 1) P = mmul(W, P);   // powers of one base commute
        W = mmul(W, W);
    }
    const M2 Mseg = W;                // A^2048

    const float* urow = u_in  + (size_t)row * TLEN;
    float*       orow = y_out + (size_t)row * TLEN;

    for (int h = 0; h < 2; ++h) {
        // ---- stage into own LDS region (transient regs; dead before scan) ----
        {
            const float4* us = (const float4*)(urow + h * HALF + w * SEG);
            float4 t0 = us[l];        float4 t1 = us[l + 64];
            float4 t2 = us[l + 128];  float4 t3 = us[l + 192];
            float4 t4 = us[l + 256];  float4 t5 = us[l + 320];
            float4 t6 = us[l + 384];  float4 t7 = us[l + 448];
            *(float4*)&wreg[4 * ((l      ) + ((l      ) >> 3))] = t0;
            *(float4*)&wreg[4 * ((l +  64) + ((l +  64) >> 3))] = t1;
            *(float4*)&wreg[4 * ((l + 128) + ((l + 128) >> 3))] = t2;
            *(float4*)&wreg[4 * ((l + 192) + ((l + 192) >> 3))] = t3;
            *(float4*)&wreg[4 * ((l + 256) + ((l + 256) >> 3))] = t4;
            *(float4*)&wreg[4 * ((l + 320) + ((l + 320) >> 3))] = t5;
            *(float4*)&wreg[4 * ((l + 384) + ((l + 384) >> 3))] = t6;
            *(float4*)&wreg[4 * ((l + 448) + ((l + 448) >> 3))] = t7;
        }
        __threadfence_block();        // wave-local DS writes visible to own reads

        // ---- chunk boundary u's via shuffle of pre-read last quad ----
        float um2, um1;
        {
            float4 q7 = *(const float4*)&wreg[4 * (9 * l + 7)];  // elems 28..31
            float pm2 = __shfl_up(q7.z, 1);
            float pm1 = __shfl_up(q7.w, 1);
            if (l == 0) {
                int gstart = h * HALF + w * SEG;
                if (gstart == 0) { um2 = u_init[2 * row + 1]; um1 = u_init[2 * row + 0]; }
                else { float2 b = *(const float2*)(urow + gstart - 2); um2 = b.x; um1 = b.y; }
            } else { um2 = pm2; um1 = pm1; }
        }

        // ---- pass 1: transpose-read quad + fused FIR + zero-state recurrence ----
        float4 v[8];
        float y1 = 0.0f, y2 = 0.0f;
        #pragma unroll
        for (int j = 0; j < 8; ++j) {
            float4 q = *(const float4*)&wreg[4 * (9 * l + j)];
            float v0 = fmaf(b2, um2, fmaf(b1, um1, b0 * q.x));
            float v1 = fmaf(b2, um1, fmaf(b1, q.x, b0 * q.y));
            float v2 = fmaf(b2, q.x, fmaf(b1, q.y, b0 * q.z));
            float v3 = fmaf(b2, q.y, fmaf(b1, q.z, b0 * q.w));
            v[j].x = v0; v[j].y = v1; v[j].z = v2; v[j].w = v3;
            float x0 = fmaf(-a1, y1, fmaf(-a2, y2, v0));
            float x1 = fmaf(-a1, x0, fmaf(-a2, y1, v1));
            float x2 = fmaf(-a1, x1, fmaf(-a2, x0, v2));
            float x3 = fmaf(-a1, x2, fmaf(-a2, x1, v3));
            y2 = x2; y1 = x3;
            um2 = q.z; um1 = q.w;
        }

        // ---- in-wave Kogge-Stone affine scan (uniform matrix; shuffle vectors) ----
        float s0 = y1, s1 = y2;
        M2 Wp = M;
        #pragma unroll
        for (int p = 0; p < 6; ++p) {
            float o0 = __shfl_up(s0, 1 << p);
            float o1 = __shfl_up(s1, 1 << p);
            if (l >= (1 << p)) {
                float n0 = fmaf(Wp.a, o0, fmaf(Wp.b, o1, s0));
                float n1 = fmaf(Wp.c, o0, fmaf(Wp.d, o1, s1));
                s0 = n0; s1 = n1;
            }
            if (p < 5) Wp = mmul(Wp, Wp);
        }
        float e0 = __shfl_up(s0, 1);
        float e1 = __shfl_up(s1, 1);
        if (l == 0) { e0 = 0.0f; e1 = 0.0f; }

        if (l == 63) {                // wave summary (zero-state segment response)
            lds[SUMS + 8 * h + 2 * w]     = s0;
            lds[SUMS + 8 * h + 2 * w + 1] = s1;
        }
        __syncthreads();              // ONE barrier per half

        // ---- cross-wave combine (4 summaries; broadcast reads) ----
        float t0, t1;                 // state before this half / before my segment
        if (h == 0) { t0 = y_init[2 * row]; t1 = y_init[2 * row + 1]; }
        else        { t0 = lds[CARRY]; t1 = lds[CARRY + 1]; }
        float c0 = t0, c1 = t1;
        #pragma unroll
        for (int j = 0; j < NW; ++j) {
            float q0 = lds[SUMS + 8 * h + 2 * j];
            float q1 = lds[SUMS + 8 * h + 2 * j + 1];
            float n0 = fmaf(Mseg.a, c0, fmaf(Mseg.b, c1, q0));
            float n1 = fmaf(Mseg.c, c0, fmaf(Mseg.d, c1, q1));
            c0 = n0; c1 = n1;
            if (j == w - 1) { t0 = c0; t1 = c1; }
        }
        if (h == 0 && tid == 0) { lds[CARRY] = c0; lds[CARRY + 1] = c1; } // read after next barrier

        // lane's incoming state: P * wave_in + exclusive in-wave prefix
        float in0 = fmaf(P.a, t0, fmaf(P.b, t1, e0));
        float in1 = fmaf(P.c, t0, fmaf(P.d, t1, e1));

        // ---- pass 2: exact recurrence, y quads straight into LDS ----
        float py1 = in0, py2 = in1;
        #pragma unroll
        for (int j = 0; j < 8; ++j) {
            float x0 = fmaf(-a1, py1, fmaf(-a2, py2, v[j].x));
            float x1 = fmaf(-a1, x0,  fmaf(-a2, py1, v[j].y));
            float x2 = fmaf(-a1, x1,  fmaf(-a2, x0,  v[j].z));
            float x3 = fmaf(-a1, x2,  fmaf(-a2, x1,  v[j].w));
            float4 q; q.x = x0; q.y = x1; q.z = x2; q.w = x3;
            *(float4*)&wreg[4 * (9 * l + j)] = q;
            py2 = x2; py1 = x3;
        }
        __threadfence_block();

        // ---- drain: coalesced LDS -> global (transient regs) ----
        {
            float4* os = (float4*)(orow + h * HALF + w * SEG);
            os[l      ] = *(const float4*)&wreg[4 * ((l      ) + ((l      ) >> 3))];
            os[l +  64] = *(const float4*)&wreg[4 * ((l +  64) + ((l +  64) >> 3))];
            os[l + 128] = *(const float4*)&wreg[4 * ((l + 128) + ((l + 128) >> 3))];
            os[l + 192] = *(const float4*)&wreg[4 * ((l + 192) + ((l + 192) >> 3))];
            os[l + 256] = *(const float4*)&wreg[4 * ((l + 256) + ((l + 256) >> 3))];
            os[l + 320] = *(const float4*)&wreg[4 * ((l + 320) + ((l + 320) >> 3))];
            os[l + 384] = *(const float4*)&wreg[4 * ((l + 384) + ((l + 384) >> 3))];
            os[l + 448] = *(const float4*)&wreg[4 * ((l + 448) + ((l + 448) >> 3))];
        }
        // next half's stage writes only this wave's own region; per-wave DS
        // ordering + the stage-top fence make this safe without a block barrier.
    }
}

extern "C" void kernel_launch(void* const* d_in, const int* in_sizes, int n_in,
                              void* d_out, int out_size, void* d_ws, size_t ws_size,
                              hipStream_t stream) {
    const float* bc    = (const float*)d_in[0];
    const float* rho   = (const float*)d_in[1];
    const float* psi   = (const float*)d_in[2];
    const float* u_in  = (const float*)d_in[3];
    const float* y_in  = (const float*)d_in[4];
    const float* u_ini = (const float*)d_in[5];
    float* y = (float*)d_out;
    const int B = in_sizes[3] / TLEN;   // 1024
    iir_kernel<<<B, NT, 0, stream>>>(bc, rho, psi, u_in, y_in, u_ini, y);
}